// Round 1
// baseline (321.306 us; speedup 1.0000x reference)
//
#include <hip/hip_runtime.h>

// Problem constants
#define NSPLIT 4
#define BC     64     // basic_c (conv input channels per split)
#define NL     64     // n_lego  (conv output channels)
#define INC    256
#define OUTC   256
#define HIN    56
#define WIN    56
#define HOUT   19
#define WOUT   58
#define WPAD   64     // padded output-w working width
#define FSTR   65     // feat LDS row stride (odd -> conflict-free)

// ---------------------------------------------------------------------------
// prep: (a) per (split,o) argmax over n_lego of aux_combination -> idx, and
//       coeff = aux_coefficients[i,o,idx];  (b) transpose lego from [n][c][kh]
//       to [kh][c][n] so the main kernel stages it with coalesced loads.
// ---------------------------------------------------------------------------
__global__ __launch_bounds__(256) void prep_kernel(
    const float* __restrict__ lego,    // [64][64][3]
    const float* __restrict__ comb,    // [4][256][64]
    const float* __restrict__ coefs,   // [4][256][64]
    float* __restrict__ coeffW,        // ws [4][256]
    int*   __restrict__ idxW,          // ws [4][256]
    float* __restrict__ lego_t)        // ws [3][64][64]
{
    const int bid = blockIdx.x, t = threadIdx.x;
    if (bid < 4) {
        const int i = bid, o = t;
        const float* p = comb + (size_t)(i * 256 + o) * 64;
        float best = p[0];
        int bi = 0;
        for (int n = 1; n < 64; ++n) {
            float v = p[n];
            if (v > best) { best = v; bi = n; }   // strict > keeps first max (jnp.argmax)
        }
        idxW[i * 256 + o]   = bi;
        coeffW[i * 256 + o] = coefs[(size_t)(i * 256 + o) * 64 + bi];
    } else {
        int e = (bid - 4) * 256 + t;              // e = kh*4096 + c*64 + n
        int kh = e >> 12, c = (e >> 6) & 63, n = e & 63;
        lego_t[e] = lego[n * 192 + c * 3 + kh];
    }
}

// ---------------------------------------------------------------------------
// Fused conv + sparse-einsum. One block per (h_out, batch). 256 threads.
//
// Stage A (per split, per kh): stage lego slice [c][n] (16KB) and x rows
//   xs[c][w] (16KB, w = output col, value = x[..][3h+kh-1][w-1], 0-padded).
//   Register tile: thread (n2=t&31, wg=t>>5) computes n={2n2,2n2+1} x 8 w.
//   xs reads are wave-uniform (broadcast, free); lego reads consecutive.
// Stage B: feat -> LDS (stride 65), then thread (w=t&63, g=t>>6) accumulates
//   out[o=g*64+m][w] += coeff[i,o]*feat[idx[i,o]][w]  (idx/coeff wave-uniform,
//   feat reads consecutive-address: conflict-free). Final store w-coalesced.
// ---------------------------------------------------------------------------
__global__ __launch_bounds__(256) void lego_main(
    const float* __restrict__ x,       // [32][256][56][56]
    const float* __restrict__ lego_t,  // [3][64][64]
    const float* __restrict__ coeffW,  // [4][256]
    const int*   __restrict__ idxW,    // [4][256]
    float* __restrict__ out)           // [32][256][19][58]
{
    __shared__ float lego_s[64 * 64];      // [c][n]
    __shared__ float xs[64 * 64];          // [c][w]
    __shared__ float feat[64 * FSTR];      // [n][w], stride 65

    const int t = threadIdx.x;
    const int h = blockIdx.x;              // 0..18
    const int b = blockIdx.y;              // 0..31

    // feat-compute mapping
    const int n2 = t & 31;                 // rows n = 2*n2, 2*n2+1
    const int wg = t >> 5;                 // w = wg*8 + j
    // out-gather mapping
    const int wo = t & 63;
    const int g  = t >> 6;

    float acc_out[64];
    #pragma unroll
    for (int m = 0; m < 64; ++m) acc_out[m] = 0.f;

    const float* xb = x + (size_t)b * (INC * HIN * WIN);

    for (int i = 0; i < NSPLIT; ++i) {
        float af0[8], af1[8];
        #pragma unroll
        for (int j = 0; j < 8; ++j) { af0[j] = 0.f; af1[j] = 0.f; }

        for (int kh = 0; kh < 3; ++kh) {
            // ---- stage lego slice (coalesced, contiguous 16KB) ----
            const float* lt = lego_t + kh * 4096;
            #pragma unroll
            for (int r = 0; r < 16; ++r) {
                int e = r * 256 + t;
                lego_s[e] = lt[e];
            }
            // ---- stage x rows: xs[c][w] = x[b][i*64+c][3h+kh-1][w-1] ----
            const int row = 3 * h + kh - 1;
            const bool rowok = (row >= 0) && (row < HIN);
            const float* xrow = xb + (size_t)(i * BC) * (HIN * WIN) + row * WIN;
            #pragma unroll
            for (int r = 0; r < 16; ++r) {
                int e = r * 256 + t;
                int c = e >> 6, w = e & 63;
                int col = w - 1;
                float v = 0.f;
                if (rowok && (unsigned)col < (unsigned)WIN)
                    v = xrow[c * (HIN * WIN) + col];
                xs[e] = v;
            }
            __syncthreads();

            // ---- accumulate over c ----
            #pragma unroll 8
            for (int c = 0; c < 64; ++c) {
                float lw0 = lego_s[c * 64 + 2 * n2];
                float lw1 = lego_s[c * 64 + 2 * n2 + 1];
                float xv[8];
                #pragma unroll
                for (int j = 0; j < 8; ++j) xv[j] = xs[c * 64 + wg * 8 + j];
                #pragma unroll
                for (int j = 0; j < 8; ++j) {
                    af0[j] = fmaf(lw0, xv[j], af0[j]);
                    af1[j] = fmaf(lw1, xv[j], af1[j]);
                }
            }
            __syncthreads();   // before restaging lego_s/xs for next kh
        }

        // ---- feat registers -> LDS ----
        #pragma unroll
        for (int j = 0; j < 8; ++j) {
            feat[(2 * n2)     * FSTR + wg * 8 + j] = af0[j];
            feat[(2 * n2 + 1) * FSTR + wg * 8 + j] = af1[j];
        }
        __syncthreads();

        // ---- sparse einsum: acc_out[m] += coeff * feat[idx][wo] ----
        #pragma unroll
        for (int m = 0; m < 64; ++m) {
            int o = g * 64 + m;
            int id   = idxW[i * 256 + o];    // wave-uniform
            float cf = coeffW[i * 256 + o];  // wave-uniform
            acc_out[m] = fmaf(cf, feat[id * FSTR + wo], acc_out[m]);
        }
        __syncthreads();   // before next split overwrites LDS
    }

    // ---- coalesced store ----
    if (wo < WOUT) {
        #pragma unroll
        for (int m = 0; m < 64; ++m) {
            int o = g * 64 + m;
            out[(((size_t)b * OUTC + o) * HOUT + h) * WOUT + wo] = acc_out[m];
        }
    }
}

extern "C" void kernel_launch(void* const* d_in, const int* in_sizes, int n_in,
                              void* d_out, int out_size, void* d_ws, size_t ws_size,
                              hipStream_t stream) {
    const float* x     = (const float*)d_in[0];   // (32,256,56,56)
    const float* lego  = (const float*)d_in[1];   // (64,64,3,1)
    const float* coefs = (const float*)d_in[2];   // (4,256,64,1,1)
    const float* comb  = (const float*)d_in[3];   // (4,256,64,1,1)
    float* out = (float*)d_out;                   // (32,256,19,58)

    float* coeffW = (float*)d_ws;                 // 1024 floats
    int*   idxW   = (int*)(coeffW + 1024);        // 1024 ints
    float* lego_t = (float*)(idxW + 1024);        // 12288 floats  (57,344 B total)

    prep_kernel<<<52, 256, 0, stream>>>(lego, comb, coefs, coeffW, idxW, lego_t);

    dim3 grid(HOUT, 32);
    lego_main<<<grid, 256, 0, stream>>>(x, lego_t, coeffW, idxW, out);
}

// Round 2
// 224.184 us; speedup vs baseline: 1.4332x; 1.4332x over previous
//
#include <hip/hip_runtime.h>

// Problem constants
#define NSPLIT 4
#define BC     64
#define NL     64
#define INC    256
#define OUTC   256
#define HIN    56
#define WIN    56
#define HOUT   19
#define WOUT   58
#define FSTR   68            // feat LDS row stride (words): 16B-aligned rows

// ---------------------------------------------------------------------------
// prep: (a) per (split,o) argmax over n_lego of aux_combination -> idx, and
//       coeff = aux_coefficients[i,o,idx];  (b) transpose lego from [n][c][kh]
//       to [kh][c][n] so the conv kernel stages it with coalesced loads.
// ---------------------------------------------------------------------------
__global__ __launch_bounds__(256) void prep_kernel(
    const float* __restrict__ lego,    // [64][64][3]
    const float* __restrict__ comb,    // [4][256][64]
    const float* __restrict__ coefs,   // [4][256][64]
    float* __restrict__ coeffW,        // ws [4][256]
    int*   __restrict__ idxW,          // ws [4][256]
    float* __restrict__ lego_t)        // ws [3][64][64]
{
    const int bid = blockIdx.x, t = threadIdx.x;
    if (bid < 4) {
        const int i = bid, o = t;
        const float* p = comb + (size_t)(i * 256 + o) * 64;
        float best = p[0];
        int bi = 0;
        for (int n = 1; n < 64; ++n) {
            float v = p[n];
            if (v > best) { best = v; bi = n; }   // strict >: first max (jnp.argmax)
        }
        idxW[i * 256 + o]   = bi;
        coeffW[i * 256 + o] = coefs[(size_t)(i * 256 + o) * 64 + bi];
    } else {
        int e = (bid - 4) * 256 + t;              // e = kh*4096 + c*64 + n
        int kh = e >> 12, c = (e >> 6) & 63, n = e & 63;
        lego_t[e] = lego[n * 192 + c * 3 + kh];
    }
}

// ---------------------------------------------------------------------------
// conv: one block per (split i, batch b, h_out). 256 threads.
// feat_i[n][w] = sum_{kh,c} lego_t[kh][c][n] * x[b][i*64+c][3h+kh-1][w-1]
//
// Thread (n4 = t&15, wq = t>>4) owns a 4n x 4w register tile:
//   per c-iter: 1x ds_read_b128 lego (16 distinct addrs, 4-lane bcast, 2-way)
//             + 1x ds_read_b128 xs  (4 distinct addrs, 16-lane bcast)
//             -> 2 LDS instrs per 16 FMAs, conflict-free.
// Next-kh lego/x staged into registers during compute (latency overlap).
// LDS 32KB total (feat transpose buffer aliases staging) -> 5 blocks/CU.
// ---------------------------------------------------------------------------
__global__ __launch_bounds__(256) void conv_kernel(
    const float* __restrict__ x,       // [32][256][56][56]
    const float* __restrict__ lego_t,  // [3][64][64]  ([kh][c][n])
    float* __restrict__ featG)         // ws [4][32][64][19][58]
{
    __shared__ float smem[8192];       // lego_s = smem[0..4095] ([c][n])
                                       // xs     = smem[4096..8191] ([c][w])
                                       // feat   = smem[0..4351] (stride 68), aliased after conv
    float* lego_s = smem;
    float* xs     = smem + 4096;

    const int t  = threadIdx.x;
    const int i  = blockIdx.x;         // 0..3
    const int h  = blockIdx.y;         // 0..18
    const int b  = blockIdx.z;         // 0..31
    const int n4 = t & 15;
    const int wq = t >> 4;

    const float* xbase = x + ((size_t)b * INC + i * BC) * (HIN * WIN);

    float acc[4][4];
    #pragma unroll
    for (int r = 0; r < 4; ++r)
        #pragma unroll
        for (int j = 0; j < 4; ++j) acc[r][j] = 0.f;

    float lgA[16], xrA[16];
    // ---- stage kh=0 into registers ----
    {
        const float* lt = lego_t;      // kh = 0
        #pragma unroll
        for (int r = 0; r < 16; ++r) lgA[r] = lt[r * 256 + t];
        const int row = 3 * h - 1;
        const bool rowok = (row >= 0);
        const float* xrow = xbase + row * WIN;
        #pragma unroll
        for (int r = 0; r < 16; ++r) {
            int e = r * 256 + t;
            int c = e >> 6, col = (e & 63) - 1;
            float v = 0.f;
            if (rowok && (unsigned)col < (unsigned)WIN) v = xrow[c * (HIN * WIN) + col];
            xrA[r] = v;
        }
        #pragma unroll
        for (int r = 0; r < 16; ++r) {
            lego_s[r * 256 + t] = lgA[r];
            xs[r * 256 + t]     = xrA[r];
        }
    }

    for (int kh = 0; kh < 3; ++kh) {
        __syncthreads();               // staged data visible

        // ---- prefetch next kh into registers (overlaps compute) ----
        float lgB[16], xrB[16];
        if (kh < 2) {
            const float* lt = lego_t + (kh + 1) * 4096;
            #pragma unroll
            for (int r = 0; r < 16; ++r) lgB[r] = lt[r * 256 + t];
            const int row = 3 * h + kh;      // (kh+1) - 1
            const bool rowok = (row < HIN);  // row >= 0 guaranteed here
            const float* xrow = xbase + row * WIN;
            #pragma unroll
            for (int r = 0; r < 16; ++r) {
                int e = r * 256 + t;
                int c = e >> 6, col = (e & 63) - 1;
                float v = 0.f;
                if (rowok && (unsigned)col < (unsigned)WIN) v = xrow[c * (HIN * WIN) + col];
                xrB[r] = v;
            }
        }

        // ---- accumulate over c ----
        #pragma unroll 8
        for (int c = 0; c < 64; ++c) {
            const float4 lw = *(const float4*)&lego_s[c * 64 + n4 * 4];
            const float4 xv = *(const float4*)&xs[c * 64 + wq * 4];
            acc[0][0] = fmaf(lw.x, xv.x, acc[0][0]);
            acc[0][1] = fmaf(lw.x, xv.y, acc[0][1]);
            acc[0][2] = fmaf(lw.x, xv.z, acc[0][2]);
            acc[0][3] = fmaf(lw.x, xv.w, acc[0][3]);
            acc[1][0] = fmaf(lw.y, xv.x, acc[1][0]);
            acc[1][1] = fmaf(lw.y, xv.y, acc[1][1]);
            acc[1][2] = fmaf(lw.y, xv.z, acc[1][2]);
            acc[1][3] = fmaf(lw.y, xv.w, acc[1][3]);
            acc[2][0] = fmaf(lw.z, xv.x, acc[2][0]);
            acc[2][1] = fmaf(lw.z, xv.y, acc[2][1]);
            acc[2][2] = fmaf(lw.z, xv.z, acc[2][2]);
            acc[2][3] = fmaf(lw.z, xv.w, acc[2][3]);
            acc[3][0] = fmaf(lw.w, xv.x, acc[3][0]);
            acc[3][1] = fmaf(lw.w, xv.y, acc[3][1]);
            acc[3][2] = fmaf(lw.w, xv.z, acc[3][2]);
            acc[3][3] = fmaf(lw.w, xv.w, acc[3][3]);
        }

        __syncthreads();               // all reads of this kh done

        if (kh < 2) {
            #pragma unroll
            for (int r = 0; r < 16; ++r) {
                lego_s[r * 256 + t] = lgB[r];
                xs[r * 256 + t]     = xrB[r];
            }
        }
    }

    // ---- register tile -> feat LDS (aliases lego_s/xs region; safe post-sync) ----
    #pragma unroll
    for (int r = 0; r < 4; ++r) {
        float4 v = make_float4(acc[r][0], acc[r][1], acc[r][2], acc[r][3]);
        *(float4*)&smem[(n4 * 4 + r) * FSTR + wq * 4] = v;
    }
    __syncthreads();

    // ---- coalesced global write: thread (wo=t&63, q=t>>6), rows n=q*16+m ----
    const int wo = t & 63;
    const int q  = t >> 6;
    if (wo < WOUT) {
        #pragma unroll
        for (int m = 0; m < 16; ++m) {
            int n = q * 16 + m;
            featG[((((size_t)i * 32 + b) * NL + n) * HOUT + h) * WOUT + wo] =
                smem[n * FSTR + wo];
        }
    }
}

// ---------------------------------------------------------------------------
// gather: out[b,o,h,w] = sum_i coeff[i,o] * feat_i[b, idx[i,o], h, w]
// Flat, one thread per output element (9,027,584 = 35264 * 256 exactly).
// ---------------------------------------------------------------------------
__global__ __launch_bounds__(256) void gather_kernel(
    const float* __restrict__ featG,   // [4][32][64][19][58]
    const float* __restrict__ coeffW,  // [4][256]
    const int*   __restrict__ idxW,    // [4][256]
    float* __restrict__ out)           // [32][256][19][58]
{
    const int e = blockIdx.x * 256 + threadIdx.x;
    const int w  = e % WOUT;
    const int t1 = e / WOUT;           // b*256*19 + o*19 + h
    const int h  = t1 % HOUT;
    const int t2 = t1 / HOUT;          // b*256 + o
    const int o  = t2 & 255;
    const int b  = t2 >> 8;

    float acc = 0.f;
    #pragma unroll
    for (int i = 0; i < NSPLIT; ++i) {
        int   id = idxW[i * 256 + o];
        float cf = coeffW[i * 256 + o];
        acc = fmaf(cf, featG[((((size_t)i * 32 + b) * NL + id) * HOUT + h) * WOUT + w], acc);
    }
    out[e] = acc;
}

extern "C" void kernel_launch(void* const* d_in, const int* in_sizes, int n_in,
                              void* d_out, int out_size, void* d_ws, size_t ws_size,
                              hipStream_t stream) {
    const float* x     = (const float*)d_in[0];   // (32,256,56,56)
    const float* lego  = (const float*)d_in[1];   // (64,64,3,1)
    const float* coefs = (const float*)d_in[2];   // (4,256,64,1,1)
    const float* comb  = (const float*)d_in[3];   // (4,256,64,1,1)
    float* out = (float*)d_out;                   // (32,256,19,58)

    float* coeffW = (float*)d_ws;                 // 1024 floats
    int*   idxW   = (int*)(coeffW + 1024);        // 1024 ints
    float* lego_t = (float*)(idxW + 1024);        // 12288 floats
    float* featG  = lego_t + 12288;               // 9,027,584 floats (~36.1 MB)

    prep_kernel<<<52, 256, 0, stream>>>(lego, comb, coefs, coeffW, idxW, lego_t);

    dim3 cgrid(NSPLIT, HOUT, 32);
    conv_kernel<<<cgrid, 256, 0, stream>>>(x, lego_t, featG);

    gather_kernel<<<35264, 256, 0, stream>>>(featG, coeffW, idxW, out);
}